// Round 12
// baseline (242.826 us; speedup 1.0000x reference)
//
#include <hip/hip_runtime.h>
#include <hip/hip_bf16.h>
#include <math.h>

// Problem constants
// B=16, T=4096, E=384, H=64; M = B*T = 65536
// Y layout: [m][0..127] = K|Q (bf16, stride 128). Q is pre-scaled by
// zsc = E^-0.5*log2(e) at k_pack (folded into Wq). V goes straight to VT.

typedef __attribute__((ext_vector_type(4))) float f32x4;
typedef __attribute__((ext_vector_type(8))) __bf16 bf16x8;

#define DEVI static __device__ __forceinline__

DEVI unsigned short f2bf(float f) {
  union { float f; unsigned int u; } x; x.f = f;
  unsigned int r = x.u + 0x7fffu + ((x.u >> 16) & 1u);
  return (unsigned short)(r >> 16);
}

DEVI unsigned int cvtpk_bf16(float lo, float hi) {
  unsigned int r;
  asm("v_cvt_pk_bf16_f32 %0, %1, %2" : "=v"(r) : "v"(lo), "v"(hi));
  return r;
}

DEVI f32x4 mfma16(bf16x8 a, bf16x8 b, f32x4 c) {
  return __builtin_amdgcn_mfma_f32_16x16x32_bf16(a, b, c, 0, 0, 0);
}

// 64-elem-wide LDS rows (128 B): XOR-swizzle at 16-B granule with row&7.
DEVI bf16x8 lds_frag(const unsigned short* buf, int row, int gran) {
  return *(const bf16x8*)(buf + row * 64 + ((gran ^ (row & 7)) << 3));
}

// async 16-B global -> LDS DMA (linear dest; swizzle applied on the GLOBAL src)
DEVI void gl_lds16(const unsigned short* g, unsigned short* l) {
  __builtin_amdgcn_global_load_lds(
      (const __attribute__((address_space(1))) unsigned int*)g,
      (__attribute__((address_space(3))) unsigned int*)l, 16, 0, 0);
}

// ---------------------------------------------------------------------------
// k_pack: WT[n][k] bf16, n in [0,192) = concat(Wk,Wq,Wv) columns, k in [0,384)
// Wq columns (n in [64,128)) are pre-scaled by zsc so attention's QK^T lands
// directly in the log2-softmax domain (Q rounded once, not twice).
// ---------------------------------------------------------------------------
__global__ __launch_bounds__(256) void k_pack(const float* __restrict__ Wk,
                                              const float* __restrict__ Wq,
                                              const float* __restrict__ Wv,
                                              unsigned short* __restrict__ WT) {
  int idx = blockIdx.x * 256 + threadIdx.x;
  if (idx >= 192 * 384) return;
  int n = idx / 384, k = idx - n * 384;
  const float* W = (n < 64) ? Wk : ((n < 128) ? Wq : Wv);
  float val = W[k * 64 + (n & 63)];
  if (n >= 64 && n < 128) val *= 0.073622223f;  // 384^-0.5 * log2(e)
  WT[idx] = f2bf(val);
}

// ---------------------------------------------------------------------------
// k_proj: [K|Q|V] = x @ [Wk|Wq|Wv];  K|Q -> Y[m][128], V -> VT[b][d][t] (fused
// transpose store, packed uint2). BM=64, BN=192, BK=64; 4 waves 2x2.
// ---------------------------------------------------------------------------
__global__ __launch_bounds__(256, 4) void k_proj(const float* __restrict__ x,
                                                 const unsigned short* __restrict__ WT,
                                                 unsigned short* __restrict__ Y,
                                                 unsigned short* __restrict__ VT) {
  __shared__ __align__(16) unsigned short As[64 * 64];
  __shared__ __align__(16) unsigned short Bs[192 * 64];
  const int tid = threadIdx.x;
  const int lane = tid & 63, wid = tid >> 6;
  const int q = lane & 15, g = lane >> 4;
  const int wm = wid >> 1, wn = wid & 1;
  const int m0 = blockIdx.x * 64;

  f32x4 acc[2][6];
#pragma unroll
  for (int mt = 0; mt < 2; ++mt)
#pragma unroll
    for (int nt = 0; nt < 6; ++nt) acc[mt][nt] = f32x4{0.f, 0.f, 0.f, 0.f};

  const int ar = tid >> 2, ap = tid & 3;  // A staging: row, 16-float quarter

  for (int ks = 0; ks < 6; ++ks) {
    // stage A: x fp32 -> bf16, 64 rows x 64 k
    const float4* xp = (const float4*)(x + (size_t)(m0 + ar) * 384 + ks * 64 + ap * 16);
#pragma unroll
    for (int cc = 0; cc < 2; ++cc) {
      float4 f0 = xp[cc * 2], f1 = xp[cc * 2 + 1];
      union { unsigned short h[8]; uint4 v; } u;
      u.h[0] = f2bf(f0.x); u.h[1] = f2bf(f0.y); u.h[2] = f2bf(f0.z); u.h[3] = f2bf(f0.w);
      u.h[4] = f2bf(f1.x); u.h[5] = f2bf(f1.y); u.h[6] = f2bf(f1.z); u.h[7] = f2bf(f1.w);
      int gran = ap * 2 + cc;
      *(uint4*)(As + ar * 64 + ((gran ^ (ar & 7)) << 3)) = u.v;
    }
    // stage B: WT rows (n-major), 192 rows x 64 k
#pragma unroll
    for (int i = 0; i < 6; ++i) {
      int c = tid + 256 * i;
      int row = c >> 3, gr = c & 7;
      uint4 w = *(const uint4*)(WT + (size_t)row * 384 + ks * 64 + gr * 8);
      *(uint4*)(Bs + row * 64 + ((gr ^ (row & 7)) << 3)) = w;
    }
    __syncthreads();
#pragma unroll
    for (int kk = 0; kk < 2; ++kk) {
      bf16x8 af[2], bfv[6];
#pragma unroll
      for (int mt = 0; mt < 2; ++mt) af[mt] = lds_frag(As, wm * 32 + mt * 16 + q, kk * 4 + g);
#pragma unroll
      for (int nt = 0; nt < 6; ++nt) bfv[nt] = lds_frag(Bs, wn * 96 + nt * 16 + q, kk * 4 + g);
#pragma unroll
      for (int mt = 0; mt < 2; ++mt)
#pragma unroll
        for (int nt = 0; nt < 6; ++nt) acc[mt][nt] = mfma16(af[mt], bfv[nt], acc[mt][nt]);
    }
    __syncthreads();
  }
  // epilogue: C/D layout col=lane&15 (n), row=4*(lane>>4)+j (m).
  // n < 128 (K|Q) -> Y[m][n]; n >= 128 (V) -> VT[b][n-128][t] packed along m.
#pragma unroll
  for (int mt = 0; mt < 2; ++mt) {
    const int mrow = m0 + wm * 32 + mt * 16 + g * 4;
#pragma unroll
    for (int nt = 0; nt < 6; ++nt) {
      const int ncol = wn * 96 + nt * 16 + q;
      if (wn == 1 && nt >= 2) {
        // V: d = ncol-128 = (nt-2)*16 + q; t = mrow..mrow+3 contiguous
        const int d = (nt - 2) * 16 + q;
        const int bb = mrow >> 12, t = mrow & 4095;
        uint2 pv;
        pv.x = cvtpk_bf16(acc[mt][nt][0], acc[mt][nt][1]);
        pv.y = cvtpk_bf16(acc[mt][nt][2], acc[mt][nt][3]);
        *(uint2*)(VT + (size_t)(bb * 64 + d) * 4096 + t) = pv;
      } else {
        size_t base = (size_t)mrow * 128 + ncol;
#pragma unroll
        for (int j = 0; j < 4; ++j) Y[base + (size_t)j * 128] = f2bf(acc[mt][nt][j]);
      }
    }
  }
}

// ---------------------------------------------------------------------------
// k_attn: flash attention, causal. R11 structure (passing base, attn 64.8us):
// 512 blocks x 8 waves; QBLOCK=128, KVBLK=64; kv-parity split; 32 q-rows per
// wave (qh=0,1); 4-slot K ring, one barrier per 2 tiles; max-free softmax.
// R12 single mechanism: V-DIRECT-FROM-L2. The LDS pipe was the saturated
// resource (~16 waves x 20 b128/iter ~ 4600 cy vs 4250 cy wall); V^T
// fragments are contiguous 16-B global rows and L2-resident (0.5 MB/batch),
// so PV's A-operands now load straight from global, hoisted before QK so
// ~1500 cy of QK+softmax hides L2 latency. LDS traffic -35%, LDS 80->48 KB,
// half the staging DMAs per barrier. P bounce + fences byte-identical to R11;
// merge scratch l moves to the (dead) Ps buffer.
// ---------------------------------------------------------------------------
__global__ __launch_bounds__(512, 4) void k_attn(const unsigned short* __restrict__ Y,
                                                 const unsigned short* __restrict__ VT,
                                                 float* __restrict__ out) {
  __shared__ __align__(16) unsigned short Ks[4][64 * 64];
  __shared__ __align__(16) unsigned short Ps[8][16 * 64];  // per-wave, reused across qh

  // id -> (xcd-affine batch, size-rank): big tiles first; rank r<16 pairs with
  // r+16 so co-scheduled blocks sum to ~constant work.
  const int id = blockIdx.x;
  const int xcd = id & 7;
  const int b = xcd * 2 + ((id >> 3) & 1);
  const int rank = id >> 4;  // 0..31
  const int i = (rank < 16) ? (31 - rank) : (rank - 16);  // q-tile index
  const int q0 = i * 128;
  const int nkv = 2 * i + 2;  // KV tiles (even)

  const int tid = threadIdx.x;
  const int lane = tid & 63, wid = tid >> 6;
  const int p = wid >> 2;   // KV parity group
  const int w4 = wid & 3;   // wave within group
  const int q = lane & 15, g = lane >> 4;

  const unsigned short* Yb = Y + (size_t)b * 4096 * 128;
  const unsigned short* Vb = VT + (size_t)b * 64 * 4096;

  // stage K tile at KV0 into ring slot S: 512 threads, one 16-B chunk each
#define STAGE(S, KV0)                                                           \
  {                                                                             \
    int r = tid >> 3, grs = (tid & 7) ^ (r & 7);                                \
    gl_lds16(Yb + (size_t)((KV0) + r) * 128 + grs * 8, Ks[S] + tid * 8);        \
  }

  STAGE(0, 0)
  STAGE(1, 64)
  __syncthreads();

  // Q fragments for both q-halves (already scaled by zsc via k_pack)
  bf16x8 qf[2][2];
#pragma unroll
  for (int qh = 0; qh < 2; ++qh) {
    const unsigned short* qp = Yb + (size_t)(q0 + w4 * 32 + qh * 16 + q) * 128 + 64;
    qf[qh][0] = *(const bf16x8*)(qp + g * 8);
    qf[qh][1] = *(const bf16x8*)(qp + 32 + g * 8);
  }

  f32x4 accO[2][4];
#pragma unroll
  for (int qh = 0; qh < 2; ++qh)
#pragma unroll
    for (int dt = 0; dt < 4; ++dt) accO[qh][dt] = f32x4{0.f, 0.f, 0.f, 0.f};
  float lsum[2] = {0.f, 0.f};

  // tiles this wave actually needs: waves 0,1 of a group stop one tile earlier
  const int mytiles = 2 * i + 1 + (w4 >> 1);
  const int nIt = nkv >> 1;  // = i+1

  // V fragment base for this lane: rows dt*16+q of VT (d-major), 16-B chunks
  const unsigned short* vRow = Vb + (size_t)q * 4096;

  for (int it = 0; it < nIt; ++it) {
    const int kt = 2 * it + p;
    const int t2 = 2 * it + 2, t3 = 2 * it + 3;
    if (t2 < nkv) STAGE(t2 & 3, t2 * 64)
    if (t3 < nkv) STAGE(t3 & 3, t3 * 64)

    if (kt < mytiles) {
      const int kv0 = kt * 64;
      const unsigned short* Kc = Ks[kt & 3];

      // ---- K fragments from LDS (read once, shared by both q-halves) ----
      bf16x8 ka0[4], ka1[4];
#pragma unroll
      for (int t = 0; t < 4; ++t) {
        ka0[t] = lds_frag(Kc, t * 16 + q, g);
        ka1[t] = lds_frag(Kc, t * 16 + q, 4 + g);
      }

      // ---- V fragments DIRECT from global (L2-resident); issued early so
      //      QK + softmax (~1500 cy) hides the load latency ----
      bf16x8 av0[4], av1[4];
#pragma unroll
      for (int dt = 0; dt < 4; ++dt) {
        const unsigned short* vp = vRow + (size_t)dt * 16 * 4096 + kv0 + g * 8;
        av0[dt] = *(const bf16x8*)vp;
        av1[dt] = *(const bf16x8*)(vp + 32);
      }

      // ---- S^T = K . Q^T for both q-halves ----
      f32x4 accS[2][4];
      __builtin_amdgcn_s_setprio(1);
#pragma unroll
      for (int qh = 0; qh < 2; ++qh)
#pragma unroll
        for (int t = 0; t < 4; ++t) {
          f32x4 z = f32x4{0.f, 0.f, 0.f, 0.f};
          z = mfma16(ka0[t], qf[qh][0], z);
          z = mfma16(ka1[t], qf[qh][1], z);
          accS[qh][t] = z;
        }
      __builtin_amdgcn_s_setprio(0);

      // ---- max-free softmax per q-half; P packed into per-wave LDS (reused)
      const bool dmw = (kv0 + 63 >= q0 + w4 * 32);  // diagonal tile for this wave
      bf16x8 bp[2][2];
#pragma unroll
      for (int qh = 0; qh < 2; ++qh) {
        if (dmw) {
          const int qrow = q0 + w4 * 32 + qh * 16 + q;
#pragma unroll
          for (int t = 0; t < 4; ++t)
#pragma unroll
            for (int j = 0; j < 4; ++j)
              if (kv0 + t * 16 + g * 4 + j > qrow) accS[qh][t][j] = -INFINITY;
        }
        float ps0 = 0.f, ps1 = 0.f;
#pragma unroll
        for (int t = 0; t < 4; ++t) {
          float p0 = __builtin_amdgcn_exp2f(accS[qh][t][0]);
          float p1 = __builtin_amdgcn_exp2f(accS[qh][t][1]);
          float p2 = __builtin_amdgcn_exp2f(accS[qh][t][2]);
          float p3 = __builtin_amdgcn_exp2f(accS[qh][t][3]);
          ps0 += p0 + p1;
          ps1 += p2 + p3;
          uint2 pv;
          pv.x = cvtpk_bf16(p0, p1);
          pv.y = cvtpk_bf16(p2, p3);
          *(uint2*)(Ps[wid] + q * 64 + ((t * 16 + g * 4) ^ ((q & 7) << 3))) = pv;
        }
        lsum[qh] += ps0 + ps1;
        asm volatile("" ::: "memory");  // pin P writes before the read-back
        bp[qh][0] = lds_frag(Ps[wid], q, g);
        bp[qh][1] = lds_frag(Ps[wid], q, 4 + g);
        asm volatile("" ::: "memory");  // pin the read before next qh's writes
      }

      // ---- O^T += V^T . P^T (V fragments already in registers) ----
      __builtin_amdgcn_s_setprio(1);
#pragma unroll
      for (int dt = 0; dt < 4; ++dt) {
#pragma unroll
        for (int qh = 0; qh < 2; ++qh) {
          accO[qh][dt] = mfma16(av0[dt], bp[qh][0], accO[qh][dt]);
          accO[qh][dt] = mfma16(av1[dt], bp[qh][1], accO[qh][dt]);
        }
      }
      __builtin_amdgcn_s_setprio(0);
    }

    __syncthreads();  // drains prefetch DMAs; frees this iteration's slots
  }
#undef STAGE

  // group-local full row sums
#pragma unroll
  for (int qh = 0; qh < 2; ++qh) {
    lsum[qh] += __shfl_xor(lsum[qh], 16);
    lsum[qh] += __shfl_xor(lsum[qh], 32);
  }

  // ---- merge parity groups: O = (O_A + O_B) / (l_A + l_B) ----
  // ring is dead: accO scratch spans Ks (32 KB); l scratch in Ps (2 KB of 16).
  float* scrO = (float*)Ks;
  float* scrL = (float*)Ps;
  const int si = (w4 * 64 + lane) * 2;
  if (p == 1) {
#pragma unroll
    for (int qh = 0; qh < 2; ++qh) {
      float* so = scrO + (si + qh) * 16;
#pragma unroll
      for (int dt = 0; dt < 4; ++dt) *(float4*)(so + dt * 4) = *(float4*)&accO[qh][dt];
      scrL[si + qh] = lsum[qh];
    }
  }
  __syncthreads();
  if (p == 0) {
#pragma unroll
    for (int qh = 0; qh < 2; ++qh) {
      const float* so = scrO + (si + qh) * 16;
      float rl = 1.0f / (lsum[qh] + scrL[si + qh]);
      const int qrow = q0 + w4 * 32 + qh * 16 + q;
      float* op = out + (size_t)(b * 4096 + qrow) * 64;
#pragma unroll
      for (int dt = 0; dt < 4; ++dt) {
        float4 ob = *(const float4*)(so + dt * 4);
        f32x4 vO;
        vO[0] = (accO[qh][dt][0] + ob.x) * rl;
        vO[1] = (accO[qh][dt][1] + ob.y) * rl;
        vO[2] = (accO[qh][dt][2] + ob.z) * rl;
        vO[3] = (accO[qh][dt][3] + ob.w) * rl;
        *(float4*)(op + dt * 16 + g * 4) = *(float4*)&vO;
      }
    }
  }
}

// ---------------------------------------------------------------------------
extern "C" void kernel_launch(void* const* d_in, const int* in_sizes, int n_in,
                              void* d_out, int out_size, void* d_ws, size_t ws_size,
                              hipStream_t stream) {
  const float* x  = (const float*)d_in[0];
  const float* Wk = (const float*)d_in[1];
  const float* Wq = (const float*)d_in[2];
  const float* Wv = (const float*)d_in[3];
  float* out = (float*)d_out;

  // workspace layout (ushorts): WT 73728 | Y 8388608 (65536x128) | VT 4194304
  unsigned short* WT = (unsigned short*)d_ws;
  unsigned short* Y  = WT + 73728;
  unsigned short* VT = Y + 8388608;

  hipLaunchKernelGGL(k_pack, dim3(288), dim3(256), 0, stream, Wk, Wq, Wv, WT);
  hipLaunchKernelGGL(k_proj, dim3(1024), dim3(256), 0, stream, x, WT, Y, VT);
  hipLaunchKernelGGL(k_attn, dim3(512), dim3(512), 0, stream, Y, VT, out);
}

// Round 13
// 86.571 us; speedup vs baseline: 2.8049x; 2.8049x over previous
//
#include <hip/hip_runtime.h>
#include <hip/hip_bf16.h>
#include <math.h>

// Problem constants
// B=16, T=4096, E=384, H=64; M = B*T = 65536
// Y layout: [m][0..127] = K|Q (bf16, stride 128). Q is pre-scaled by
// zsc = E^-0.5*log2(e) at k_pack (folded into Wq). V goes straight to VT.

typedef __attribute__((ext_vector_type(4))) float f32x4;
typedef __attribute__((ext_vector_type(8))) __bf16 bf16x8;

#define DEVI static __device__ __forceinline__

DEVI unsigned short f2bf(float f) {
  union { float f; unsigned int u; } x; x.f = f;
  unsigned int r = x.u + 0x7fffu + ((x.u >> 16) & 1u);
  return (unsigned short)(r >> 16);
}

DEVI unsigned int cvtpk_bf16(float lo, float hi) {
  unsigned int r;
  asm("v_cvt_pk_bf16_f32 %0, %1, %2" : "=v"(r) : "v"(lo), "v"(hi));
  return r;
}

DEVI f32x4 mfma16(bf16x8 a, bf16x8 b, f32x4 c) {
  return __builtin_amdgcn_mfma_f32_16x16x32_bf16(a, b, c, 0, 0, 0);
}

// 64-elem-wide LDS rows (128 B): XOR-swizzle at 16-B granule with row&7.
DEVI bf16x8 lds_frag(const unsigned short* buf, int row, int gran) {
  return *(const bf16x8*)(buf + row * 64 + ((gran ^ (row & 7)) << 3));
}

// async 16-B global -> LDS DMA (linear dest; swizzle applied on the GLOBAL src)
DEVI void gl_lds16(const unsigned short* g, unsigned short* l) {
  __builtin_amdgcn_global_load_lds(
      (const __attribute__((address_space(1))) unsigned int*)g,
      (__attribute__((address_space(3))) unsigned int*)l, 16, 0, 0);
}

// ---------------------------------------------------------------------------
// k_pack: WT[n][k] bf16, n in [0,192) = concat(Wk,Wq,Wv) columns, k in [0,384)
// Wq columns (n in [64,128)) are pre-scaled by zsc so attention's QK^T lands
// directly in the log2-softmax domain (Q rounded once, not twice).
// ---------------------------------------------------------------------------
__global__ __launch_bounds__(256) void k_pack(const float* __restrict__ Wk,
                                              const float* __restrict__ Wq,
                                              const float* __restrict__ Wv,
                                              unsigned short* __restrict__ WT) {
  int idx = blockIdx.x * 256 + threadIdx.x;
  if (idx >= 192 * 384) return;
  int n = idx / 384, k = idx - n * 384;
  const float* W = (n < 64) ? Wk : ((n < 128) ? Wq : Wv);
  float val = W[k * 64 + (n & 63)];
  if (n >= 64 && n < 128) val *= 0.073622223f;  // 384^-0.5 * log2(e)
  WT[idx] = f2bf(val);
}

// ---------------------------------------------------------------------------
// k_proj: [K|Q|V] = x @ [Wk|Wq|Wv];  K|Q -> Y[m][128], V -> VT[b][d][t] (fused
// transpose store, packed uint2). BM=64, BN=192, BK=64; 4 waves 2x2.
// ---------------------------------------------------------------------------
__global__ __launch_bounds__(256, 4) void k_proj(const float* __restrict__ x,
                                                 const unsigned short* __restrict__ WT,
                                                 unsigned short* __restrict__ Y,
                                                 unsigned short* __restrict__ VT) {
  __shared__ __align__(16) unsigned short As[64 * 64];
  __shared__ __align__(16) unsigned short Bs[192 * 64];
  const int tid = threadIdx.x;
  const int lane = tid & 63, wid = tid >> 6;
  const int q = lane & 15, g = lane >> 4;
  const int wm = wid >> 1, wn = wid & 1;
  const int m0 = blockIdx.x * 64;

  f32x4 acc[2][6];
#pragma unroll
  for (int mt = 0; mt < 2; ++mt)
#pragma unroll
    for (int nt = 0; nt < 6; ++nt) acc[mt][nt] = f32x4{0.f, 0.f, 0.f, 0.f};

  const int ar = tid >> 2, ap = tid & 3;  // A staging: row, 16-float quarter

  for (int ks = 0; ks < 6; ++ks) {
    // stage A: x fp32 -> bf16, 64 rows x 64 k
    const float4* xp = (const float4*)(x + (size_t)(m0 + ar) * 384 + ks * 64 + ap * 16);
#pragma unroll
    for (int cc = 0; cc < 2; ++cc) {
      float4 f0 = xp[cc * 2], f1 = xp[cc * 2 + 1];
      union { unsigned short h[8]; uint4 v; } u;
      u.h[0] = f2bf(f0.x); u.h[1] = f2bf(f0.y); u.h[2] = f2bf(f0.z); u.h[3] = f2bf(f0.w);
      u.h[4] = f2bf(f1.x); u.h[5] = f2bf(f1.y); u.h[6] = f2bf(f1.z); u.h[7] = f2bf(f1.w);
      int gran = ap * 2 + cc;
      *(uint4*)(As + ar * 64 + ((gran ^ (ar & 7)) << 3)) = u.v;
    }
    // stage B: WT rows (n-major), 192 rows x 64 k
#pragma unroll
    for (int i = 0; i < 6; ++i) {
      int c = tid + 256 * i;
      int row = c >> 3, gr = c & 7;
      uint4 w = *(const uint4*)(WT + (size_t)row * 384 + ks * 64 + gr * 8);
      *(uint4*)(Bs + row * 64 + ((gr ^ (row & 7)) << 3)) = w;
    }
    __syncthreads();
#pragma unroll
    for (int kk = 0; kk < 2; ++kk) {
      bf16x8 af[2], bfv[6];
#pragma unroll
      for (int mt = 0; mt < 2; ++mt) af[mt] = lds_frag(As, wm * 32 + mt * 16 + q, kk * 4 + g);
#pragma unroll
      for (int nt = 0; nt < 6; ++nt) bfv[nt] = lds_frag(Bs, wn * 96 + nt * 16 + q, kk * 4 + g);
#pragma unroll
      for (int mt = 0; mt < 2; ++mt)
#pragma unroll
        for (int nt = 0; nt < 6; ++nt) acc[mt][nt] = mfma16(af[mt], bfv[nt], acc[mt][nt]);
    }
    __syncthreads();
  }
  // epilogue: C/D layout col=lane&15 (n), row=4*(lane>>4)+j (m).
  // n < 128 (K|Q) -> Y[m][n]; n >= 128 (V) -> VT[b][n-128][t] packed along m.
#pragma unroll
  for (int mt = 0; mt < 2; ++mt) {
    const int mrow = m0 + wm * 32 + mt * 16 + g * 4;
#pragma unroll
    for (int nt = 0; nt < 6; ++nt) {
      const int ncol = wn * 96 + nt * 16 + q;
      if (wn == 1 && nt >= 2) {
        // V: d = ncol-128 = (nt-2)*16 + q; t = mrow..mrow+3 contiguous
        const int d = (nt - 2) * 16 + q;
        const int bb = mrow >> 12, t = mrow & 4095;
        uint2 pv;
        pv.x = cvtpk_bf16(acc[mt][nt][0], acc[mt][nt][1]);
        pv.y = cvtpk_bf16(acc[mt][nt][2], acc[mt][nt][3]);
        *(uint2*)(VT + (size_t)(bb * 64 + d) * 4096 + t) = pv;
      } else {
        size_t base = (size_t)mrow * 128 + ncol;
#pragma unroll
        for (int j = 0; j < 4; ++j) Y[base + (size_t)j * 128] = f2bf(acc[mt][nt][j]);
      }
    }
  }
}

// ---------------------------------------------------------------------------
// k_attn: flash attention, causal. R11 structure (passing base, attn 64.8us):
// 512 blocks x 8 waves; QBLOCK=128, KVBLK=64; kv-parity split; 32 q-rows per
// wave (qh=0,1); 4-slot K+V ring, one barrier per 2 tiles; max-free softmax;
// V staged in LDS (R12's V-direct was an 8KB-stride pattern -> L2 thrash).
// R13 single mechanism: KV-PERMUTED K STAGING -> LANE-LOCAL P. Staging K rows
// with the bit-permutation kv(L) = (L&32)|((L&12)<<1)|((L&16)>>2)|(L&3) makes
// QK^T's C/D element (t,j) hold kv = (t>>1)*32 + g*8 + (t&1)*4 + j -- exactly
// the PV B-fragment order. P fragments are assembled IN-REGISTER from the
// cvt_pk results: no Ps buffer, no P LDS writes/reads, no fences, and the
// R7-class TBAA hazard is gone by construction. ka/av/qf LDS patterns are
// byte-identical to R11; only the mask formula is relabeled.
// ---------------------------------------------------------------------------
__global__ __launch_bounds__(512, 4) void k_attn(const unsigned short* __restrict__ Y,
                                                 const unsigned short* __restrict__ VT,
                                                 float* __restrict__ out) {
  __shared__ __align__(16) unsigned short Ks[4][64 * 64];
  __shared__ __align__(16) unsigned short Vs[4][64 * 64];

  // id -> (xcd-affine batch, size-rank): big tiles first; rank r<16 pairs with
  // r+16 so co-scheduled blocks sum to ~constant work.
  const int id = blockIdx.x;
  const int xcd = id & 7;
  const int b = xcd * 2 + ((id >> 3) & 1);
  const int rank = id >> 4;  // 0..31
  const int i = (rank < 16) ? (31 - rank) : (rank - 16);  // q-tile index
  const int q0 = i * 128;
  const int nkv = 2 * i + 2;  // KV tiles (even)

  const int tid = threadIdx.x;
  const int lane = tid & 63, wid = tid >> 6;
  const int p = wid >> 2;   // KV parity group
  const int w4 = wid & 3;   // wave within group
  const int q = lane & 15, g = lane >> 4;

  const unsigned short* Yb = Y + (size_t)b * 4096 * 128;
  const unsigned short* Vb = VT + (size_t)b * 64 * 4096;

  // stage tile at KV0 into ring slot S. K rows are staged PERMUTED so that
  // LDS row L holds global kv row kvperm(L); V rows are d-indexed (linear).
#define STAGE(S, KV0)                                                           \
  {                                                                             \
    int r = tid >> 3, grs = (tid & 7) ^ (r & 7);                                \
    int kp = (r & 32) | ((r & 12) << 1) | ((r & 16) >> 2) | (r & 3);            \
    gl_lds16(Yb + (size_t)((KV0) + kp) * 128 + grs * 8, Ks[S] + tid * 8);       \
    gl_lds16(Vb + (size_t)r * 4096 + (KV0) + grs * 8, Vs[S] + tid * 8);         \
  }

  STAGE(0, 0)
  STAGE(1, 64)
  __syncthreads();

  // Q fragments for both q-halves (already scaled by zsc via k_pack)
  bf16x8 qf[2][2];
#pragma unroll
  for (int qh = 0; qh < 2; ++qh) {
    const unsigned short* qp = Yb + (size_t)(q0 + w4 * 32 + qh * 16 + q) * 128 + 64;
    qf[qh][0] = *(const bf16x8*)(qp + g * 8);
    qf[qh][1] = *(const bf16x8*)(qp + 32 + g * 8);
  }

  f32x4 accO[2][4];
#pragma unroll
  for (int qh = 0; qh < 2; ++qh)
#pragma unroll
    for (int dt = 0; dt < 4; ++dt) accO[qh][dt] = f32x4{0.f, 0.f, 0.f, 0.f};
  float lsum[2] = {0.f, 0.f};

  // tiles this wave actually needs: waves 0,1 of a group stop one tile earlier
  const int mytiles = 2 * i + 1 + (w4 >> 1);
  const int nIt = nkv >> 1;  // = i+1

  for (int it = 0; it < nIt; ++it) {
    const int kt = 2 * it + p;
    const int t2 = 2 * it + 2, t3 = 2 * it + 3;
    if (t2 < nkv) STAGE(t2 & 3, t2 * 64)
    if (t3 < nkv) STAGE(t3 & 3, t3 * 64)

    if (kt < mytiles) {
      const int kv0 = kt * 64;
      const unsigned short* Kc = Ks[kt & 3];
      const unsigned short* Vc = Vs[kt & 3];

      // ---- S^T = K . Q^T for both q-halves (K fragments read once).
      // With permuted staging, accS[qh][t][j] = S^T[kv0 + (t>>1)*32 + g*8 +
      // (t&1)*4 + j][qrow(base+q)].
      bf16x8 ka0[4], ka1[4];
#pragma unroll
      for (int t = 0; t < 4; ++t) {
        ka0[t] = lds_frag(Kc, t * 16 + q, g);
        ka1[t] = lds_frag(Kc, t * 16 + q, 4 + g);
      }
      f32x4 accS[2][4];
      __builtin_amdgcn_s_setprio(1);
#pragma unroll
      for (int qh = 0; qh < 2; ++qh)
#pragma unroll
        for (int t = 0; t < 4; ++t) {
          f32x4 z = f32x4{0.f, 0.f, 0.f, 0.f};
          z = mfma16(ka0[t], qf[qh][0], z);
          z = mfma16(ka1[t], qf[qh][1], z);
          accS[qh][t] = z;
        }
      __builtin_amdgcn_s_setprio(0);

      // ---- max-free softmax per q-half; P assembled IN-REGISTER ----
      const bool dmw = (kv0 + 63 >= q0 + w4 * 32);  // diagonal tile for this wave
      bf16x8 bp[2][2];
#pragma unroll
      for (int qh = 0; qh < 2; ++qh) {
        if (dmw) {
          const int qrow = q0 + w4 * 32 + qh * 16 + q;
#pragma unroll
          for (int t = 0; t < 4; ++t)
#pragma unroll
            for (int j = 0; j < 4; ++j) {
              const int kvl = ((t >> 1) << 5) + (g << 3) + ((t & 1) << 2) + j;
              if (kv0 + kvl > qrow) accS[qh][t][j] = -INFINITY;
            }
        }
        float pp[4][4];
        float ps0 = 0.f, ps1 = 0.f;
#pragma unroll
        for (int t = 0; t < 4; ++t) {
          pp[t][0] = __builtin_amdgcn_exp2f(accS[qh][t][0]);
          pp[t][1] = __builtin_amdgcn_exp2f(accS[qh][t][1]);
          pp[t][2] = __builtin_amdgcn_exp2f(accS[qh][t][2]);
          pp[t][3] = __builtin_amdgcn_exp2f(accS[qh][t][3]);
          ps0 += pp[t][0] + pp[t][1];
          ps1 += pp[t][2] + pp[t][3];
        }
        lsum[qh] += ps0 + ps1;
        // bp0 holds P[q][kv0 + g*8 + e] (e: t=0 j=0..3, t=1 j=0..3);
        // bp1 the same for kv0+32 (t=2,3). Pure register assembly.
        uint4 u0, u1;
        u0.x = cvtpk_bf16(pp[0][0], pp[0][1]);
        u0.y = cvtpk_bf16(pp[0][2], pp[0][3]);
        u0.z = cvtpk_bf16(pp[1][0], pp[1][1]);
        u0.w = cvtpk_bf16(pp[1][2], pp[1][3]);
        u1.x = cvtpk_bf16(pp[2][0], pp[2][1]);
        u1.y = cvtpk_bf16(pp[2][2], pp[2][3]);
        u1.z = cvtpk_bf16(pp[3][0], pp[3][1]);
        u1.w = cvtpk_bf16(pp[3][2], pp[3][3]);
        bp[qh][0] = __builtin_bit_cast(bf16x8, u0);
        bp[qh][1] = __builtin_bit_cast(bf16x8, u1);
      }

      // ---- O^T += V^T . P^T (V fragments read once, used by both q-halves)
      __builtin_amdgcn_s_setprio(1);
#pragma unroll
      for (int dt = 0; dt < 4; ++dt) {
        bf16x8 av0 = lds_frag(Vc, dt * 16 + q, g);
        bf16x8 av1 = lds_frag(Vc, dt * 16 + q, 4 + g);
#pragma unroll
        for (int qh = 0; qh < 2; ++qh) {
          accO[qh][dt] = mfma16(av0, bp[qh][0], accO[qh][dt]);
          accO[qh][dt] = mfma16(av1, bp[qh][1], accO[qh][dt]);
        }
      }
      __builtin_amdgcn_s_setprio(0);
    }

    __syncthreads();  // drains prefetch DMAs; frees this iteration's slots
  }
#undef STAGE

  // group-local full row sums
#pragma unroll
  for (int qh = 0; qh < 2; ++qh) {
    lsum[qh] += __shfl_xor(lsum[qh], 16);
    lsum[qh] += __shfl_xor(lsum[qh], 32);
  }

  // ---- merge parity groups: O = (O_A + O_B) / (l_A + l_B) ----
  // ring is dead: accO scratch spans Ks (32 KB); l scratch at Vs base (2 KB).
  float* scrO = (float*)Ks;
  float* scrL = (float*)Vs;
  const int si = (w4 * 64 + lane) * 2;
  if (p == 1) {
#pragma unroll
    for (int qh = 0; qh < 2; ++qh) {
      float* so = scrO + (si + qh) * 16;
#pragma unroll
      for (int dt = 0; dt < 4; ++dt) *(float4*)(so + dt * 4) = *(float4*)&accO[qh][dt];
      scrL[si + qh] = lsum[qh];
    }
  }
  __syncthreads();
  if (p == 0) {
#pragma unroll
    for (int qh = 0; qh < 2; ++qh) {
      const float* so = scrO + (si + qh) * 16;
      float rl = 1.0f / (lsum[qh] + scrL[si + qh]);
      const int qrow = q0 + w4 * 32 + qh * 16 + q;
      float* op = out + (size_t)(b * 4096 + qrow) * 64;
#pragma unroll
      for (int dt = 0; dt < 4; ++dt) {
        float4 ob = *(const float4*)(so + dt * 4);
        f32x4 vO;
        vO[0] = (accO[qh][dt][0] + ob.x) * rl;
        vO[1] = (accO[qh][dt][1] + ob.y) * rl;
        vO[2] = (accO[qh][dt][2] + ob.z) * rl;
        vO[3] = (accO[qh][dt][3] + ob.w) * rl;
        *(float4*)(op + dt * 16 + g * 4) = *(float4*)&vO;
      }
    }
  }
}

// ---------------------------------------------------------------------------
extern "C" void kernel_launch(void* const* d_in, const int* in_sizes, int n_in,
                              void* d_out, int out_size, void* d_ws, size_t ws_size,
                              hipStream_t stream) {
  const float* x  = (const float*)d_in[0];
  const float* Wk = (const float*)d_in[1];
  const float* Wq = (const float*)d_in[2];
  const float* Wv = (const float*)d_in[3];
  float* out = (float*)d_out;

  // workspace layout (ushorts): WT 73728 | Y 8388608 (65536x128) | VT 4194304
  unsigned short* WT = (unsigned short*)d_ws;
  unsigned short* Y  = WT + 73728;
  unsigned short* VT = Y + 8388608;

  hipLaunchKernelGGL(k_pack, dim3(288), dim3(256), 0, stream, Wk, Wq, Wv, WT);
  hipLaunchKernelGGL(k_proj, dim3(1024), dim3(256), 0, stream, x, WT, Y, VT);
  hipLaunchKernelGGL(k_attn, dim3(512), dim3(512), 0, stream, Y, VT, out);
}